// Round 20
// baseline (166.047 us; speedup 1.0000x reference)
//
#include <hip/hip_runtime.h>
#include <hip/hip_bf16.h>
#include <cstddef>

#define HW 4096   // 64*64

typedef __attribute__((ext_vector_type(8))) short bf16x8;
typedef __attribute__((ext_vector_type(4))) float f32x4;

__device__ __forceinline__ unsigned short f2b(float v) {
  __hip_bfloat16 b = __float2bfloat16(v);           // round-to-nearest
  return *reinterpret_cast<unsigned short*>(&b);
}
__device__ __forceinline__ float b2f(unsigned short u) {
  return __bfloat162float(*reinterpret_cast<const __hip_bfloat16*>(&u));
}

// ---------------------------------------------------------------------------
// x transpose+convert: xb[n][px][ci] (bf16) from x[n][ci][px] (f32).
// grid (64 px-tiles, 4 ci-tiles, 6 img), block 256, LDS 64x65.
// ---------------------------------------------------------------------------
__global__ __launch_bounds__(256) void txp_kernel(const float* __restrict__ x,
                                                  unsigned short* __restrict__ xb) {
  const int n = blockIdx.z, p0 = blockIdx.x * 64, ci0 = blockIdx.y * 64;
  const int t = threadIdx.x;
  __shared__ float Tl[64][65];
#pragma unroll
  for (int pass = 0; pass < 16; ++pass) {
    int ci = pass * 4 + (t >> 6), px = t & 63;
    Tl[ci][px] = x[((size_t)n * 256 + ci0 + ci) * HW + p0 + px];
  }
  __syncthreads();
#pragma unroll
  for (int pass = 0; pass < 16; ++pass) {
    int px = pass * 4 + (t >> 6), ci = t & 63;
    xb[((size_t)n * HW + p0 + px) * 256 + ci0 + ci] = f2b(Tl[ci][px]);
  }
}

// W convert to bf16 (layout [co][ci] kept — it IS the MFMA B fragment layout)
__global__ __launch_bounds__(256) void wcv_kernel(const float* __restrict__ Wq,
                                                  const float* __restrict__ Ws,
                                                  unsigned short* __restrict__ wb) {
  int i = blockIdx.x * 256 + threadIdx.x;   // 0..131071
  const float* W = (i < 65536) ? Wq : Ws;
  wb[i] = f2b(W[i & 65535]);
}

// ---------------------------------------------------------------------------
// MFMA projection + bias + fused per-head l2norm.
// grid (256 px-tiles of 16, 4 co-groups of 64, 6 img), block 256 = 4 waves.
// Wave wv: 16px x 16co (co = co0 + wv*16 + (l&15)), K=256 via 8 MFMAs.
// Outputs: n==0 -> qb bf16 (scaled), n>=1 -> sb bf16.
// ---------------------------------------------------------------------------
__global__ __launch_bounds__(256) void proj_kernel(
    const unsigned short* __restrict__ xb, const unsigned short* __restrict__ wb,
    const float* __restrict__ bq, const float* __restrict__ bs,
    const float* __restrict__ scale,
    unsigned short* __restrict__ qb, unsigned short* __restrict__ sb) {
  const int n   = blockIdx.z;
  const int p0  = blockIdx.x * 16;
  const int co0 = blockIdx.y * 64;
  const int t   = threadIdx.x;
  const int wv  = t >> 6;
  const int l   = t & 63;
  const float* __restrict__ B = (n == 0) ? bq : bs;
  const unsigned short* __restrict__ Wb = wb + (size_t)(n == 0 ? 0 : 1) * 65536;

  __shared__ float Sl[16][68];
  __shared__ float ssl[16][2];

  const size_t arow = ((size_t)n * HW + p0 + (l & 15)) * 256 + (l >> 4) * 8;
  const size_t brow = ((size_t)(co0 + wv * 16 + (l & 15))) * 256 + (l >> 4) * 8;

  f32x4 acc = {0.f, 0.f, 0.f, 0.f};
#pragma unroll
  for (int kc = 0; kc < 8; ++kc) {
    bf16x8 a = *(const bf16x8*)&xb[arow + kc * 32];
    bf16x8 b = *(const bf16x8*)&Wb[brow + kc * 32];
    acc = __builtin_amdgcn_mfma_f32_16x16x32_bf16(a, b, acc, 0, 0, 0);
  }

  // D: row px=(l>>4)*4+r, col co=(l&15). Add bias, stage.
  const float bias = B[co0 + wv * 16 + (l & 15)];
#pragma unroll
  for (int r = 0; r < 4; ++r)
    Sl[(l >> 4) * 4 + r][wv * 16 + (l & 15)] = acc[r] + bias;
  __syncthreads();

  if (t < 32) {
    int px = t & 15, hd = t >> 4;
    float ss = 0.f;
#pragma unroll
    for (int dd = 0; dd < 32; ++dd) {
      float v = Sl[px][hd * 32 + dd];
      ss += v * v;
    }
    ssl[px][hd] = fmaxf(sqrtf(ss), 1e-12f);
  }
  __syncthreads();

  const float qsc = scale[0] * 0.17677669529663687f;   // scale * HD^-0.5
#pragma unroll
  for (int pass = 0; pass < 4; ++pass) {
    int idx = pass * 256 + t;
    int px = idx >> 6, co = idx & 63;
    float v = Sl[px][co] / ssl[px][co >> 5];
    if (n == 0)
      qb[(size_t)(p0 + px) * 256 + co0 + co] = f2b(v * qsc);
    else
      sb[((size_t)(n - 1) * HW + p0 + px) * 256 + co0 + co] = f2b(v);
  }
}

// ---------------------------------------------------------------------------
// Patch aggregation (bf16 s input) -> cb (bf16) [8][2560][32], mask[2560].
// ---------------------------------------------------------------------------
__global__ __launch_bounds__(256) void agg_kernel(
    const float* __restrict__ delta, const unsigned short* __restrict__ sb,
    unsigned short* __restrict__ cb, float* __restrict__ mask) {
  const int s = blockIdx.x;
  const int k = blockIdx.y;
  const int t = threadIdx.x;
  __shared__ float fgl[16];
  const int sy = (s >> 4) * 4, sx = (s & 15) * 4;
  if (t < 16) {
    int y0 = (sy + (t >> 2)) * 8, x0 = (sx + (t & 3)) * 8;
    fgl[t] = delta[(size_t)k * 512 * 512 + (size_t)y0 * 512 + x0];
  }
  __syncthreads();
  const int h = t >> 5, d = t & 31;
  float af = 0.f, ab = 0.f;
#pragma unroll
  for (int l = 0; l < 16; ++l) {
    int pix = (sy + (l >> 2)) * 64 + sx + (l & 3);
    float sv = b2f(sb[((size_t)k * HW + pix) * 256 + h * 32 + d]);
    float f = fgl[l];
    af += f * sv;
    ab += (1.f - f) * sv;
  }
  float ssf = af * af, ssb = ab * ab;
#pragma unroll
  for (int m = 1; m <= 16; m <<= 1) {
    ssf += __shfl_xor(ssf, m);
    ssb += __shfl_xor(ssb, m);
  }
  float vf = af / fmaxf(sqrtf(ssf), 1e-12f);
  float vb = ab / fmaxf(sqrtf(ssb), 1e-12f);
  const int jf = k * 512 + s, jb = jf + 256;
  cb[((size_t)h * 2560 + jf) * 32 + d] = f2b(vf);
  cb[((size_t)h * 2560 + jb) * 32 + d] = f2b(vb);
  if (t == 0) {
    float fs = 0.f;
#pragma unroll
    for (int l = 0; l < 16; ++l) fs += fgl[l];
    mask[jf] = (fs < 1.f) ? -1e30f : 0.f;
    mask[jb] = ((16.f - fs) < 1.f) ? -1e30f : 0.f;
  }
}

// ---------------------------------------------------------------------------
// Attention via bf16 MFMA 16x16x32 (verified, round 18).
// ---------------------------------------------------------------------------
__global__ __launch_bounds__(256) void attn_kernel(
    const unsigned short* __restrict__ qb, const unsigned short* __restrict__ cb,
    const float* __restrict__ mask, float* __restrict__ xo) {
  const int t = threadIdx.x;
  const int wv = t >> 6;
  const int l = t & 63;
  const int h = blockIdx.y;
  const int p0 = blockIdx.x * 64 + wv * 16;

  __shared__ float ml[2560];
  for (int i = t; i < 2560; i += 256) ml[i] = mask[i];

  const bf16x8 a = *(const bf16x8*)&qb[(size_t)(p0 + (l & 15)) * 256 + h * 32 + (l >> 4) * 8];
  __syncthreads();

  float num[4] = {0.f, 0.f, 0.f, 0.f}, den[4] = {0.f, 0.f, 0.f, 0.f};
  const size_t cbase = (size_t)h * 2560 * 32 + ((size_t)(l >> 4)) * 8;

  for (int j0 = 0; j0 < 2560; j0 += 16) {
    bf16x8 b = *(const bf16x8*)&cb[cbase + (size_t)(j0 + (l & 15)) * 32];
    f32x4 dacc = {0.f, 0.f, 0.f, 0.f};
    dacc = __builtin_amdgcn_mfma_f32_16x16x32_bf16(a, b, dacc, 0, 0, 0);
    float m = ml[j0 + (l & 15)];
    float cv = ((j0 & 511) < 256) ? 1.f : 0.f;
#pragma unroll
    for (int r = 0; r < 4; ++r) {
      float e = __expf(dacc[r] + m);
      den[r] += e;
      num[r] += cv * e;
    }
  }

#pragma unroll
  for (int r = 0; r < 4; ++r) {
#pragma unroll
    for (int msk = 1; msk <= 8; msk <<= 1) {
      den[r] += __shfl_xor(den[r], msk);
      num[r] += __shfl_xor(num[r], msk);
    }
  }
  if ((l & 15) == 0) {
#pragma unroll
    for (int r = 0; r < 4; ++r) {
      int px = p0 + (l >> 4) * 4 + r;
      xo[(size_t)h * HW + px] = num[r] / den[r];
    }
  }
}

// ---------------------------------------------------------------------------
// Conv, ci-split partials (verified, round 19).
// ---------------------------------------------------------------------------
template <int CIC, int KS, int PAD, int COT>
__global__ __launch_bounds__(256) void conv_split(
    const float* __restrict__ in, const float* __restrict__ w,
    float* __restrict__ pp, int CI) {
  constexpr int R = 4 + KS - 1;
  constexpr int C = 64 + 2 * PAD;
  const int t   = threadIdx.x;
  const int y0  = blockIdx.x * 4;
  const int co0 = blockIdx.y * COT;
  const int cb0 = blockIdx.z * CIC;
  const int CO  = gridDim.y * COT;

  __shared__ float Xl[CIC][R][C];
  __shared__ float Wl[CIC][KS * KS][COT];

  const int xi = t & 63;
  const int yr = t >> 6;

  float acc[COT];
#pragma unroll
  for (int c = 0; c < COT; ++c) acc[c] = 0.f;

  for (int idx = t; idx < CIC * R * C; idx += 256) {
    int ci = idx / (R * C), rem = idx % (R * C), pr = rem / C, pc = rem % C;
    int iy = y0 + pr - PAD, ix = pc - PAD;
    float v = 0.f;
    if (iy >= 0 && iy < 64 && ix >= 0 && ix < 64)
      v = in[(size_t)(cb0 + ci) * HW + iy * 64 + ix];
    Xl[ci][pr][pc] = v;
  }
  for (int idx = t; idx < CIC * KS * KS * COT; idx += 256) {
    int ci = idx / (KS * KS * COT), rem = idx % (KS * KS * COT);
    int kk = rem / COT, c = rem % COT;
    Wl[ci][kk][c] = w[(size_t)((co0 + c) * CI + cb0 + ci) * KS * KS + kk];
  }
  __syncthreads();

#pragma unroll
  for (int ci = 0; ci < CIC; ++ci)
#pragma unroll
    for (int ky = 0; ky < KS; ++ky)
#pragma unroll
      for (int kx = 0; kx < KS; ++kx) {
        float xv = Xl[ci][yr + ky][xi + kx];
        if constexpr (COT % 4 == 0) {
          const float4* w4 = (const float4*)&Wl[ci][ky * KS + kx][0];
#pragma unroll
          for (int c4 = 0; c4 < COT / 4; ++c4) {
            float4 wv = w4[c4];
            acc[c4 * 4 + 0] += xv * wv.x;
            acc[c4 * 4 + 1] += xv * wv.y;
            acc[c4 * 4 + 2] += xv * wv.z;
            acc[c4 * 4 + 3] += xv * wv.w;
          }
        } else {
#pragma unroll
          for (int c = 0; c < COT; ++c) acc[c] += xv * Wl[ci][ky * KS + kx][c];
        }
      }

  const int p = (y0 + yr) * 64 + xi;
  float* o = pp + (size_t)blockIdx.z * CO * HW;
#pragma unroll
  for (int c = 0; c < COT; ++c)
    o[(size_t)(co0 + c) * HW + p] = acc[c];
}

__global__ __launch_bounds__(256) void conv_merge(
    const float* __restrict__ pp, const float* __restrict__ b,
    float* __restrict__ out, int S, int CO) {
  const int idx = blockIdx.x * 256 + threadIdx.x;
  const int c = idx >> 12;
  float v = b[c];
  const size_t stride = (size_t)CO * HW;
  for (int s = 0; s < S; ++s) v += pp[(size_t)s * stride + idx];
  out[idx] = v;
}

// ---------------------------------------------------------------------------
// GroupNorm stats, two-stage.
// ---------------------------------------------------------------------------
__global__ __launch_bounds__(256) void gnstatsA(const float* __restrict__ in,
                                                float* __restrict__ stp, int cpg) {
  __shared__ float sh[256], sh2[256];
  const int g = blockIdx.x, b = blockIdx.y, t = threadIdx.x;
  const int n = cpg * HW;
  const int chunk = n >> 4;
  const float* __restrict__ base = in + (size_t)g * n + (size_t)b * chunk;
  float s = 0.f, ss = 0.f;
  for (int i = t; i < chunk; i += 256) {
    float v = base[i];
    s += v;
    ss += v * v;
  }
  sh[t] = s; sh2[t] = ss;
  __syncthreads();
  for (int w = 128; w > 0; w >>= 1) {
    if (t < w) { sh[t] += sh[t + w]; sh2[t] += sh2[t + w]; }
    __syncthreads();
  }
  if (t == 0) { stp[(g * 16 + b) * 2] = sh[0]; stp[(g * 16 + b) * 2 + 1] = sh2[0]; }
}

__global__ __launch_bounds__(64) void gnstatsB(const float* __restrict__ stp,
                                               float* __restrict__ st, int cpg) {
  const int g = blockIdx.x;
  if (threadIdx.x == 0) {
    float S = 0.f, SS = 0.f;
    for (int b = 0; b < 16; ++b) { S += stp[(g * 16 + b) * 2]; SS += stp[(g * 16 + b) * 2 + 1]; }
    float n = (float)(cpg * HW);
    float mean = S / n;
    float var = SS / n - mean * mean;
    st[g * 2] = mean;
    st[g * 2 + 1] = 1.0f / sqrtf(var + 1e-5f);
  }
}

__global__ __launch_bounds__(256) void gn_apply(
    const float* __restrict__ in, float* __restrict__ out, const float* __restrict__ st,
    const float* __restrict__ gs, const float* __restrict__ gb, int cpg) {
  const int idx = blockIdx.x * 256 + threadIdx.x;
  const int c = idx >> 12;
  const int g = c / cpg;
  float v = (in[idx] - st[g * 2]) * st[g * 2 + 1] * gs[c] + gb[c];
  out[idx] = fmaxf(v, 0.f);
}

// ---------------------------------------------------------------------------
extern "C" void kernel_launch(void* const* d_in, const int* in_sizes, int n_in,
                              void* d_out, int out_size, void* d_ws, size_t ws_size,
                              hipStream_t stream) {
  const float* x     = (const float*)d_in[0];
  const float* delta = (const float*)d_in[1];
  const float* Wq    = (const float*)d_in[2];
  const float* bq    = (const float*)d_in[3];
  const float* Ws    = (const float*)d_in[4];
  const float* bs    = (const float*)d_in[5];
  const float* scale = (const float*)d_in[6];
  const float* c1w = (const float*)d_in[7],  *c1b = (const float*)d_in[8];
  const float* g1s = (const float*)d_in[9],  *g1b = (const float*)d_in[10];
  const float* c2w = (const float*)d_in[11], *c2b = (const float*)d_in[12];
  const float* g2s = (const float*)d_in[13], *g2b = (const float*)d_in[14];
  const float* c3w = (const float*)d_in[15], *c3b = (const float*)d_in[16];
  const float* g3s = (const float*)d_in[17], *g3b = (const float*)d_in[18];

  float* ws = (float*)d_ws;
  // bf16 regions expressed in f32 slot counts:
  unsigned short* sb = (unsigned short*)ws;            // 5,242,880 u16 = 2,621,440 f
  unsigned short* xb = (unsigned short*)(ws + 2621440);// 6,291,456 u16 = 3,145,728 f
  unsigned short* qb = (unsigned short*)(ws + 5767168);// 1,048,576 u16 =   524,288 f
  unsigned short* cb = (unsigned short*)(ws + 6291456);//   655,360 u16 =   327,680 f
  float* mask = ws + 6619136;                          //     2,560
  float* xo   = mask + 2560;                           //    32,768
  float* st   = xo + 32768;                            //        32
  float* stp  = st + 32;                               //       512
  unsigned short* wb = (unsigned short*)(stp + 512);   //   131,072 u16 = 65,536 f
  // conv temps overlay the dead sb+xb region (needs 3,276,800 f <= 5,767,168 f):
  float* pp = ws;                                      // 2,097,152
  float* t1 = ws + 2097152;                            //    65,536
  float* a1 = t1 + 65536;                              //    65,536
  float* t2 = a1 + 65536;                              //   262,144
  float* a2 = t2 + 262144;                             //   262,144
  float* t3 = a2 + 262144;                             //   524,288
  // total: 6,720,544 f ~= 25.6 MB (< proven 34.1 MB floor)

  txp_kernel<<<dim3(64, 4, 6), 256, 0, stream>>>(x, xb);
  wcv_kernel<<<512, 256, 0, stream>>>(Wq, Ws, wb);
  proj_kernel<<<dim3(256, 4, 6), 256, 0, stream>>>(xb, wb, bq, bs, scale, qb, sb);
  agg_kernel<<<dim3(256, 5), 256, 0, stream>>>(delta, sb, cb, mask);
  attn_kernel<<<dim3(64, 8), 256, 0, stream>>>(qb, cb, mask, xo);

  conv_split<4, 5, 2, 2><<<dim3(16, 8, 2), 256, 0, stream>>>(xo, c1w, pp, 8);
  conv_merge<<<256, 256, 0, stream>>>(pp, c1b, t1, 2, 16);
  gnstatsA<<<dim3(4, 16), 256, 0, stream>>>(t1, stp, 4);
  gnstatsB<<<4, 64, 0, stream>>>(stp, st, 4);
  gn_apply<<<256, 256, 0, stream>>>(t1, a1, st, g1s, g1b, 4);

  conv_split<8, 3, 1, 4><<<dim3(16, 16, 2), 256, 0, stream>>>(a1, c2w, pp, 16);
  conv_merge<<<1024, 256, 0, stream>>>(pp, c2b, t2, 2, 64);
  gnstatsA<<<dim3(4, 16), 256, 0, stream>>>(t2, stp + 128, 16);
  gnstatsB<<<4, 64, 0, stream>>>(stp + 128, st + 8, 16);
  gn_apply<<<1024, 256, 0, stream>>>(t2, a2, st + 8, g2s, g2b, 16);

  conv_split<16, 3, 1, 8><<<dim3(16, 16, 4), 256, 0, stream>>>(a2, c3w, pp, 64);
  conv_merge<<<2048, 256, 0, stream>>>(pp, c3b, t3, 4, 128);
  gnstatsA<<<dim3(4, 16), 256, 0, stream>>>(t3, stp + 256, 32);
  gnstatsB<<<4, 64, 0, stream>>>(stp + 256, st + 16, 32);
  gn_apply<<<2048, 256, 0, stream>>>(t3, (float*)d_out, st + 16, g3s, g3b, 32);
}

// Round 21
// 124.618 us; speedup vs baseline: 1.3325x; 1.3325x over previous
//
#include <hip/hip_runtime.h>
#include <hip/hip_bf16.h>
#include <cstddef>

#define HW 4096   // 64*64

typedef __attribute__((ext_vector_type(8))) short bf16x8;
typedef __attribute__((ext_vector_type(4))) float f32x4;

__device__ __forceinline__ unsigned short f2b(float v) {
  __hip_bfloat16 b = __float2bfloat16(v);           // round-to-nearest
  return *reinterpret_cast<unsigned short*>(&b);
}
__device__ __forceinline__ float b2f(unsigned short u) {
  return __bfloat162float(*reinterpret_cast<const __hip_bfloat16*>(&u));
}

// ---------------------------------------------------------------------------
// x transpose+convert: xb[n][px][ci] (bf16) from x[n][ci][px] (f32).
// ---------------------------------------------------------------------------
__global__ __launch_bounds__(256) void txp_kernel(const float* __restrict__ x,
                                                  unsigned short* __restrict__ xb) {
  const int n = blockIdx.z, p0 = blockIdx.x * 64, ci0 = blockIdx.y * 64;
  const int t = threadIdx.x;
  __shared__ float Tl[64][65];
#pragma unroll
  for (int pass = 0; pass < 16; ++pass) {
    int ci = pass * 4 + (t >> 6), px = t & 63;
    Tl[ci][px] = x[((size_t)n * 256 + ci0 + ci) * HW + p0 + px];
  }
  __syncthreads();
#pragma unroll
  for (int pass = 0; pass < 16; ++pass) {
    int px = pass * 4 + (t >> 6), ci = t & 63;
    xb[((size_t)n * HW + p0 + px) * 256 + ci0 + ci] = f2b(Tl[ci][px]);
  }
}

// W convert to bf16 ([co][ci] layout kept — it IS the MFMA B fragment layout)
__global__ __launch_bounds__(256) void wcv_kernel(const float* __restrict__ Wq,
                                                  const float* __restrict__ Ws,
                                                  unsigned short* __restrict__ wb) {
  int i = blockIdx.x * 256 + threadIdx.x;   // 0..131071
  const float* W = (i < 65536) ? Wq : Ws;
  wb[i] = f2b(W[i & 65535]);
}

// ---------------------------------------------------------------------------
// MFMA projection, register-blocked: block = 128px x 64co (4 waves on px),
// wave = 32px x 64co via acc[2][4] (8 independent MFMA chains, 64 MFMA/wave).
// In-register epilogue: bias + per-head l2norm via shfl over 16 col-lanes.
// grid (24576/128 = 192, 4). n = image = row>>12 (128 | 4096).
// ---------------------------------------------------------------------------
__global__ __launch_bounds__(256) void proj_kernel(
    const unsigned short* __restrict__ xb, const unsigned short* __restrict__ wb,
    const float* __restrict__ bq, const float* __restrict__ bs,
    const float* __restrict__ scale,
    unsigned short* __restrict__ qb, unsigned short* __restrict__ sb) {
  const int row0 = blockIdx.x * 128;
  const int n    = row0 >> 12;          // image
  const int co0  = blockIdx.y * 64;
  const int t    = threadIdx.x;
  const int wv   = t >> 6;
  const int l    = t & 63;
  const float* __restrict__ B = (n == 0) ? bq : bs;
  const unsigned short* __restrict__ Wb = wb + (size_t)(n == 0 ? 0 : 1) * 65536;
  const int prow = row0 + wv * 32;

  const size_t ar0 = ((size_t)prow + (l & 15)) * 256 + (l >> 4) * 8;
  const size_t ar1 = ar0 + 16 * 256;
  size_t br[4];
#pragma unroll
  for (int b = 0; b < 4; ++b)
    br[b] = ((size_t)(co0 + b * 16 + (l & 15))) * 256 + (l >> 4) * 8;

  f32x4 acc[2][4];
#pragma unroll
  for (int a = 0; a < 2; ++a)
#pragma unroll
    for (int b = 0; b < 4; ++b) acc[a][b] = (f32x4){0.f, 0.f, 0.f, 0.f};

#pragma unroll
  for (int kc = 0; kc < 8; ++kc) {
    bf16x8 a0 = *(const bf16x8*)&xb[ar0 + kc * 32];
    bf16x8 a1 = *(const bf16x8*)&xb[ar1 + kc * 32];
#pragma unroll
    for (int b = 0; b < 4; ++b) {
      bf16x8 bb = *(const bf16x8*)&Wb[br[b] + kc * 32];
      acc[0][b] = __builtin_amdgcn_mfma_f32_16x16x32_bf16(a0, bb, acc[0][b], 0, 0, 0);
      acc[1][b] = __builtin_amdgcn_mfma_f32_16x16x32_bf16(a1, bb, acc[1][b], 0, 0, 0);
    }
  }

  float bias[4];
#pragma unroll
  for (int b = 0; b < 4; ++b) bias[b] = B[co0 + b * 16 + (l & 15)];
  const float qsc = scale[0] * 0.17677669529663687f;   // scale * HD^-0.5

  // D: px = prow + a*16 + (l>>4)*4 + r ; co = co0 + b*16 + (l&15)
  // head0 = b{0,1}, head1 = b{2,3} (co0 is 64-aligned)
#pragma unroll
  for (int a = 0; a < 2; ++a) {
#pragma unroll
    for (int r = 0; r < 4; ++r) {
      float v0 = acc[a][0][r] + bias[0];
      float v1 = acc[a][1][r] + bias[1];
      float v2 = acc[a][2][r] + bias[2];
      float v3 = acc[a][3][r] + bias[3];
      float s0 = v0 * v0 + v1 * v1;
      float s1 = v2 * v2 + v3 * v3;
#pragma unroll
      for (int m = 1; m <= 8; m <<= 1) {
        s0 += __shfl_xor(s0, m);
        s1 += __shfl_xor(s1, m);
      }
      float n0 = fmaxf(sqrtf(s0), 1e-12f);
      float n1 = fmaxf(sqrtf(s1), 1e-12f);
      v0 /= n0; v1 /= n0; v2 /= n1; v3 /= n1;
      const int px = prow + a * 16 + (l >> 4) * 4 + r;
      if (n == 0) {
        size_t o = (size_t)px * 256 + co0 + (l & 15);
        qb[o +  0] = f2b(v0 * qsc);
        qb[o + 16] = f2b(v1 * qsc);
        qb[o + 32] = f2b(v2 * qsc);
        qb[o + 48] = f2b(v3 * qsc);
      } else {
        size_t o = ((size_t)(px - 4096 * 1) + (size_t)(n - 1) * HW - (size_t)(n - 1) * HW) * 0; // (unused)
        size_t so = ((size_t)(px - 4096) ) * 256 + co0 + (l & 15); // px already includes n*4096
        sb[so +  0] = f2b(v0);
        sb[so + 16] = f2b(v1);
        sb[so + 32] = f2b(v2);
        sb[so + 48] = f2b(v3);
      }
    }
  }
}

// ---------------------------------------------------------------------------
// Patch aggregation (bf16 s input) -> cb (bf16) [8][2560][32], mask[2560].
// ---------------------------------------------------------------------------
__global__ __launch_bounds__(256) void agg_kernel(
    const float* __restrict__ delta, const unsigned short* __restrict__ sb,
    unsigned short* __restrict__ cb, float* __restrict__ mask) {
  const int s = blockIdx.x;
  const int k = blockIdx.y;
  const int t = threadIdx.x;
  __shared__ float fgl[16];
  const int sy = (s >> 4) * 4, sx = (s & 15) * 4;
  if (t < 16) {
    int y0 = (sy + (t >> 2)) * 8, x0 = (sx + (t & 3)) * 8;
    fgl[t] = delta[(size_t)k * 512 * 512 + (size_t)y0 * 512 + x0];
  }
  __syncthreads();
  const int h = t >> 5, d = t & 31;
  float af = 0.f, ab = 0.f;
#pragma unroll
  for (int l = 0; l < 16; ++l) {
    int pix = (sy + (l >> 2)) * 64 + sx + (l & 3);
    float sv = b2f(sb[((size_t)k * HW + pix) * 256 + h * 32 + d]);
    float f = fgl[l];
    af += f * sv;
    ab += (1.f - f) * sv;
  }
  float ssf = af * af, ssb = ab * ab;
#pragma unroll
  for (int m = 1; m <= 16; m <<= 1) {
    ssf += __shfl_xor(ssf, m);
    ssb += __shfl_xor(ssb, m);
  }
  float vf = af / fmaxf(sqrtf(ssf), 1e-12f);
  float vb = ab / fmaxf(sqrtf(ssb), 1e-12f);
  const int jf = k * 512 + s, jb = jf + 256;
  cb[((size_t)h * 2560 + jf) * 32 + d] = f2b(vf);
  cb[((size_t)h * 2560 + jb) * 32 + d] = f2b(vb);
  if (t == 0) {
    float fs = 0.f;
#pragma unroll
    for (int l = 0; l < 16; ++l) fs += fgl[l];
    mask[jf] = (fs < 1.f) ? -1e30f : 0.f;
    mask[jb] = ((16.f - fs) < 1.f) ? -1e30f : 0.f;
  }
}

// ---------------------------------------------------------------------------
// Attention via bf16 MFMA 16x16x32 (verified, round 18).
// ---------------------------------------------------------------------------
__global__ __launch_bounds__(256) void attn_kernel(
    const unsigned short* __restrict__ qb, const unsigned short* __restrict__ cb,
    const float* __restrict__ mask, float* __restrict__ xo) {
  const int t = threadIdx.x;
  const int wv = t >> 6;
  const int l = t & 63;
  const int h = blockIdx.y;
  const int p0 = blockIdx.x * 64 + wv * 16;

  __shared__ float ml[2560];
  for (int i = t; i < 2560; i += 256) ml[i] = mask[i];

  const bf16x8 a = *(const bf16x8*)&qb[(size_t)(p0 + (l & 15)) * 256 + h * 32 + (l >> 4) * 8];
  __syncthreads();

  float num[4] = {0.f, 0.f, 0.f, 0.f}, den[4] = {0.f, 0.f, 0.f, 0.f};
  const size_t cbase = (size_t)h * 2560 * 32 + ((size_t)(l >> 4)) * 8;

  for (int j0 = 0; j0 < 2560; j0 += 16) {
    bf16x8 b = *(const bf16x8*)&cb[cbase + (size_t)(j0 + (l & 15)) * 32];
    f32x4 dacc = {0.f, 0.f, 0.f, 0.f};
    dacc = __builtin_amdgcn_mfma_f32_16x16x32_bf16(a, b, dacc, 0, 0, 0);
    float m = ml[j0 + (l & 15)];
    float cv = ((j0 & 511) < 256) ? 1.f : 0.f;
#pragma unroll
    for (int r = 0; r < 4; ++r) {
      float e = __expf(dacc[r] + m);
      den[r] += e;
      num[r] += cv * e;
    }
  }

#pragma unroll
  for (int r = 0; r < 4; ++r) {
#pragma unroll
    for (int msk = 1; msk <= 8; msk <<= 1) {
      den[r] += __shfl_xor(den[r], msk);
      num[r] += __shfl_xor(num[r], msk);
    }
  }
  if ((l & 15) == 0) {
#pragma unroll
    for (int r = 0; r < 4; ++r) {
      int px = p0 + (l >> 4) * 4 + r;
      xo[(size_t)h * HW + px] = num[r] / den[r];
    }
  }
}

// ---------------------------------------------------------------------------
// Conv, ci-split partials (verified, round 19).
// ---------------------------------------------------------------------------
template <int CIC, int KS, int PAD, int COT>
__global__ __launch_bounds__(256) void conv_split(
    const float* __restrict__ in, const float* __restrict__ w,
    float* __restrict__ pp, int CI) {
  constexpr int R = 4 + KS - 1;
  constexpr int C = 64 + 2 * PAD;
  const int t   = threadIdx.x;
  const int y0  = blockIdx.x * 4;
  const int co0 = blockIdx.y * COT;
  const int cb0 = blockIdx.z * CIC;
  const int CO  = gridDim.y * COT;

  __shared__ float Xl[CIC][R][C];
  __shared__ float Wl[CIC][KS * KS][COT];

  const int xi = t & 63;
  const int yr = t >> 6;

  float acc[COT];
#pragma unroll
  for (int c = 0; c < COT; ++c) acc[c] = 0.f;

  for (int idx = t; idx < CIC * R * C; idx += 256) {
    int ci = idx / (R * C), rem = idx % (R * C), pr = rem / C, pc = rem % C;
    int iy = y0 + pr - PAD, ix = pc - PAD;
    float v = 0.f;
    if (iy >= 0 && iy < 64 && ix >= 0 && ix < 64)
      v = in[(size_t)(cb0 + ci) * HW + iy * 64 + ix];
    Xl[ci][pr][pc] = v;
  }
  for (int idx = t; idx < CIC * KS * KS * COT; idx += 256) {
    int ci = idx / (KS * KS * COT), rem = idx % (KS * KS * COT);
    int kk = rem / COT, c = rem % COT;
    Wl[ci][kk][c] = w[(size_t)((co0 + c) * CI + cb0 + ci) * KS * KS + kk];
  }
  __syncthreads();

#pragma unroll
  for (int ci = 0; ci < CIC; ++ci)
#pragma unroll
    for (int ky = 0; ky < KS; ++ky)
#pragma unroll
      for (int kx = 0; kx < KS; ++kx) {
        float xv = Xl[ci][yr + ky][xi + kx];
        if constexpr (COT % 4 == 0) {
          const float4* w4 = (const float4*)&Wl[ci][ky * KS + kx][0];
#pragma unroll
          for (int c4 = 0; c4 < COT / 4; ++c4) {
            float4 wv = w4[c4];
            acc[c4 * 4 + 0] += xv * wv.x;
            acc[c4 * 4 + 1] += xv * wv.y;
            acc[c4 * 4 + 2] += xv * wv.z;
            acc[c4 * 4 + 3] += xv * wv.w;
          }
        } else {
#pragma unroll
          for (int c = 0; c < COT; ++c) acc[c] += xv * Wl[ci][ky * KS + kx][c];
        }
      }

  const int p = (y0 + yr) * 64 + xi;
  float* o = pp + (size_t)blockIdx.z * CO * HW;
#pragma unroll
  for (int c = 0; c < COT; ++c)
    o[(size_t)(co0 + c) * HW + p] = acc[c];
}

// ---------------------------------------------------------------------------
// merge_stats: out = bias + sum of S partials; per-block {sum, sumsq} -> stp.
// ---------------------------------------------------------------------------
__global__ __launch_bounds__(256) void merge_stats(
    const float* __restrict__ pp, const float* __restrict__ b,
    float* __restrict__ out, float* __restrict__ stp, int S, int CO) {
  __shared__ float sh[256], sh2[256];
  const int t = threadIdx.x;
  const int idx = blockIdx.x * 256 + t;
  const int c = idx >> 12;
  float v = b[c];
  const size_t stride = (size_t)CO * HW;
  for (int s = 0; s < S; ++s) v += pp[(size_t)s * stride + idx];
  out[idx] = v;
  sh[t] = v; sh2[t] = v * v;
  __syncthreads();
  for (int w = 128; w > 0; w >>= 1) {
    if (t < w) { sh[t] += sh[t + w]; sh2[t] += sh2[t + w]; }
    __syncthreads();
  }
  if (t == 0) { stp[blockIdx.x * 2] = sh[0]; stp[blockIdx.x * 2 + 1] = sh2[0]; }
}

// ---------------------------------------------------------------------------
// gn_apply: finalize group stats from stp (bpg partial blocks/group) + apply.
// Block covers 256 consecutive idx -> single channel -> single group.
// ---------------------------------------------------------------------------
__global__ __launch_bounds__(256) void gn_apply(
    const float* __restrict__ in, float* __restrict__ out, const float* __restrict__ stp,
    const float* __restrict__ gs, const float* __restrict__ gb, int cpg, int bpg) {
  __shared__ float sh[256], sh2[256];
  const int t = threadIdx.x;
  const int idx = blockIdx.x * 256 + t;
  const int c = idx >> 12;
  const int g = c / cpg;
  float s = 0.f, ss = 0.f;
  for (int i = t; i < bpg; i += 256) {
    s  += stp[(g * bpg + i) * 2];
    ss += stp[(g * bpg + i) * 2 + 1];
  }
  sh[t] = s; sh2[t] = ss;
  __syncthreads();
  for (int w = 128; w > 0; w >>= 1) {
    if (t < w) { sh[t] += sh[t + w]; sh2[t] += sh2[t + w]; }
    __syncthreads();
  }
  const float nn = (float)(cpg * HW);
  const float mean = sh[0] / nn;
  const float var = sh2[0] / nn - mean * mean;
  const float rstd = 1.0f / sqrtf(var + 1e-5f);
  float v = (in[idx] - mean) * rstd * gs[c] + gb[c];
  out[idx] = fmaxf(v, 0.f);
}

// ---------------------------------------------------------------------------
extern "C" void kernel_launch(void* const* d_in, const int* in_sizes, int n_in,
                              void* d_out, int out_size, void* d_ws, size_t ws_size,
                              hipStream_t stream) {
  const float* x     = (const float*)d_in[0];
  const float* delta = (const float*)d_in[1];
  const float* Wq    = (const float*)d_in[2];
  const float* bq    = (const float*)d_in[3];
  const float* Ws    = (const float*)d_in[4];
  const float* bs    = (const float*)d_in[5];
  const float* scale = (const float*)d_in[6];
  const float* c1w = (const float*)d_in[7],  *c1b = (const float*)d_in[8];
  const float* g1s = (const float*)d_in[9],  *g1b = (const float*)d_in[10];
  const float* c2w = (const float*)d_in[11], *c2b = (const float*)d_in[12];
  const float* g2s = (const float*)d_in[13], *g2b = (const float*)d_in[14];
  const float* c3w = (const float*)d_in[15], *c3b = (const float*)d_in[16];
  const float* g3s = (const float*)d_in[17], *g3b = (const float*)d_in[18];

  float* ws = (float*)d_ws;
  unsigned short* sb = (unsigned short*)ws;             // 5,242,880 u16 = 2,621,440 f
  unsigned short* xb = (unsigned short*)(ws + 2621440); // 6,291,456 u16 = 3,145,728 f
  unsigned short* qb = (unsigned short*)(ws + 5767168); // 1,048,576 u16 =   524,288 f
  unsigned short* cb = (unsigned short*)(ws + 6291456); //   655,360 u16 =   327,680 f
  float* mask = ws + 6619136;                           //     2,560
  float* xo   = mask + 2560;                            //    32,768
  float* stp  = xo + 32768;                             //     4,096
  unsigned short* wb = (unsigned short*)(stp + 4096);   //   131,072 u16 = 65,536 f
  // conv temps overlay the dead sb+xb region (3,276,800 f <= 5,767,168 f):
  float* pp = ws;                                       // 2,097,152
  float* t1 = ws + 2097152;                             //    65,536
  float* a1 = t1 + 65536;                               //    65,536
  float* t2 = a1 + 65536;                               //   262,144
  float* a2 = t2 + 262144;                              //   262,144
  float* t3 = a2 + 262144;                              //   524,288
  // total ~= 25.6 MB

  txp_kernel<<<dim3(64, 4, 6), 256, 0, stream>>>(x, xb);
  wcv_kernel<<<512, 256, 0, stream>>>(Wq, Ws, wb);
  proj_kernel<<<dim3(192, 4), 256, 0, stream>>>(xb, wb, bq, bs, scale, qb, sb);
  agg_kernel<<<dim3(256, 5), 256, 0, stream>>>(delta, sb, cb, mask);
  attn_kernel<<<dim3(64, 8), 256, 0, stream>>>(qb, cb, mask, xo);

  conv_split<4, 5, 2, 2><<<dim3(16, 8, 2), 256, 0, stream>>>(xo, c1w, pp, 8);
  merge_stats<<<256, 256, 0, stream>>>(pp, c1b, t1, stp, 2, 16);
  gn_apply<<<256, 256, 0, stream>>>(t1, a1, stp, g1s, g1b, 4, 64);

  conv_split<8, 3, 1, 4><<<dim3(16, 16, 2), 256, 0, stream>>>(a1, c2w, pp, 16);
  merge_stats<<<1024, 256, 0, stream>>>(pp, c2b, t2, stp, 2, 64);
  gn_apply<<<1024, 256, 0, stream>>>(t2, a2, stp, g2s, g2b, 16, 256);

  conv_split<16, 3, 1, 8><<<dim3(16, 16, 4), 256, 0, stream>>>(a2, c3w, pp, 64);
  merge_stats<<<2048, 256, 0, stream>>>(pp, c3b, t3, stp, 4, 128);
  gn_apply<<<2048, 256, 0, stream>>>(t3, (float*)d_out, stp, g3s, g3b, 32, 512);
}